// Round 16
// baseline (118.414 us; speedup 1.0000x reference)
//
#include <hip/hip_runtime.h>
#include <hip/hip_fp16.h>

// Problem constants
constexpr int B_  = 8;
constexpr int H_  = 64;
constexpr int W_  = 64;
constexpr int C_  = 256;
constexpr int CG_ = 32;    // g/f output channels
constexpr int CH_ = 128;   // h output channels
constexpr int NQ_ = 4096;  // H*W
constexpr int NM_ = 1024;  // (H/2)*(W/2)
constexpr int XP_ = 66;    // padded spatial dim

constexpr int GP_ = 1048576;   // g/f partial plane stride (f16 elems)
constexpr int HP_ = 4194304;   // h partial plane stride

constexpr int NWPK_ = 12 * 9 * 8 * 64 * 8;   // 589824 Wpk elems
constexpr int NWOK_ = 16 * 4 * 64 * 8;       // 32768 Wok elems
constexpr int NXC_  = B_ * XP_ * XP_ * 32;   // 1115136 Xpad half8-chunks

typedef __attribute__((ext_vector_type(8))) _Float16 half8;
typedef __attribute__((ext_vector_type(4))) _Float16 half4;
typedef __attribute__((ext_vector_type(4))) float    f32x4;

// ---------------------------------------------------------------------------
// Prep (single launch): Xpad f16 (zero-padded input) + Wpk + Wok + bc
// ---------------------------------------------------------------------------
__global__ void prep_all_k(const float* __restrict__ X,
                           const float* __restrict__ Wg, const float* __restrict__ Wf,
                           const float* __restrict__ Wh, const float* __restrict__ Wo,
                           const float* __restrict__ bg, const float* __restrict__ bf,
                           const float* __restrict__ bh,
                           _Float16* __restrict__ Xpad, _Float16* __restrict__ Wpk,
                           _Float16* __restrict__ Wok, float* __restrict__ bc) {
    int i = blockIdx.x * 256 + threadIdx.x;
    if (i < NXC_) {
        // Xpad chunk
        int c8 = i & 31;
        int px = i >> 5;
        int xx = px % XP_;
        int t  = px / XP_;
        int yy = t % XP_;
        int b  = t / XP_;
        half8 v = (half8)(_Float16)0.f;
        if (yy >= 1 && yy <= 64 && xx >= 1 && xx <= 64) {
            const float* s = X + (((size_t)(b * 64 + yy - 1) * 64) + (xx - 1)) * 256 + c8 * 8;
            float4 a  = *reinterpret_cast<const float4*>(s);
            float4 b2 = *reinterpret_cast<const float4*>(s + 4);
            v[0] = (_Float16)a.x;  v[1] = (_Float16)a.y;
            v[2] = (_Float16)a.z;  v[3] = (_Float16)a.w;
            v[4] = (_Float16)b2.x; v[5] = (_Float16)b2.y;
            v[6] = (_Float16)b2.z; v[7] = (_Float16)b2.w;
        }
        *reinterpret_cast<half8*>(Xpad + (size_t)i * 8) = v;
        return;
    }
    int iw = i - NXC_;
    if (iw < NWPK_) {
        int j    = iw & 7;
        int lane = (iw >> 3) & 63;
        int ks   = (iw >> 9) & 7;
        int tap  = (iw >> 12) % 9;
        int co16 = iw / 36864;
        int co = co16 * 16 + (lane & 15);
        int kk = tap * 256 + ks * 32 + (lane >> 4) * 8 + j;
        float v;
        if (co < 32)      v = Wg[(size_t)kk * 32  + co];
        else if (co < 64) v = Wf[(size_t)kk * 32  + (co - 32)];
        else              v = Wh[(size_t)kk * 128 + (co - 64)];
        Wpk[iw] = (_Float16)v;
        return;
    }
    int i2 = iw - NWPK_;
    if (i2 < NWOK_) {
        int j    = i2 & 7;
        int lane = (i2 >> 3) & 63;
        int ks   = (i2 >> 9) & 3;
        int co16 = i2 >> 11;
        int co = co16 * 16 + (lane & 15);
        int k  = ks * 32 + (lane >> 4) * 8 + j;
        Wok[i2] = (_Float16)Wo[(size_t)k * 256 + co];
        return;
    }
    int co = i2 - NWOK_;
    if (co < 192)
        bc[co] = (co < 32) ? bg[co] : (co < 64) ? bf[co - 32] : bh[co - 64];
}

// ---------------------------------------------------------------------------
// Fused 3x3 convs via f16 MFMA — ky-split, HALF-ROW (32 px) blocks.
// Block = (ky, b, y, xh): 4 waves of M32xN48, LDS 17.4 KB, VGPR<=64 via
// __launch_bounds__(256,8) -> 8 blocks/CU = 8 waves/SIMD. Latency hiding by
// TLP (no manual prefetch). Stages 34-px window from zero-padded Xpad f16.
// ---------------------------------------------------------------------------
__global__ __launch_bounds__(256, 8) void conv_mfma_k(
        const _Float16* __restrict__ Xpad, const _Float16* __restrict__ Wpk,
        const float* __restrict__ bc,
        _Float16* __restrict__ gpart, _Float16* __restrict__ fpart,
        _Float16* __restrict__ hpart) {
    __shared__ char lds[34 * 512];   // 17408 B
    int bid = blockIdx.x;
    int lg  = (bid & 7) * 384 + (bid >> 3);   // bijective XCD map (3072 = 8*384)
    int ky  = lg % 3;
    int t   = lg / 3;          // 0..1023
    int xh  = t & 1;
    int y   = (t >> 1) & 63;
    int b   = t >> 7;
    int tid = threadIdx.x;
    int nw  = tid >> 6;        // co slice 0..3
    int l   = tid & 63;
    int lr  = l & 15;
    int lk  = l >> 4;

    // stage 34-px window of Xpad row (b, y+ky): xx = xh*32 .. xh*32+33
    {
        const float4* src = reinterpret_cast<const float4*>(
            Xpad + (((size_t)(b * XP_ + y + ky) * XP_) + xh * 32) * 256);
        for (int c = tid; c < 34 * 32; c += 256) {
            int q = c >> 5;
            float4 v = src[c];
            *reinterpret_cast<float4*>(lds + ((c * 16) ^ ((q & 7) << 4))) = v;
        }
    }
    __syncthreads();

    f32x4 acc[2][3];
#pragma unroll
    for (int mi = 0; mi < 2; ++mi)
#pragma unroll
        for (int nj = 0; nj < 3; ++nj) acc[mi][nj] = (f32x4)0.f;

    int tap0 = ky * 3;
#pragma unroll
    for (int st = 0; st < 24; ++st) {
        int kx = st >> 3, ks = st & 7;
        const _Float16* wp = Wpk +
            ((((size_t)(nw * 3) * 9 + tap0 + kx) * 8 + ks) * 64 + l) * 8;
        half8 w0 = *reinterpret_cast<const half8*>(wp);
        half8 w1 = *reinterpret_cast<const half8*>(wp + 36864);
        half8 w2 = *reinterpret_cast<const half8*>(wp + 73728);
        half8 af[2];
#pragma unroll
        for (int mi = 0; mi < 2; ++mi) {
            int q  = mi * 16 + lr + kx;        // 0..33
            int ad = (q * 512 + ks * 64 + lk * 16) ^ ((q & 7) << 4);
            af[mi] = *reinterpret_cast<const half8*>(lds + ad);
        }
#pragma unroll
        for (int mi = 0; mi < 2; ++mi)
            acc[mi][0] = __builtin_amdgcn_mfma_f32_16x16x32_f16(af[mi], w0, acc[mi][0], 0, 0, 0);
#pragma unroll
        for (int mi = 0; mi < 2; ++mi)
            acc[mi][1] = __builtin_amdgcn_mfma_f32_16x16x32_f16(af[mi], w1, acc[mi][1], 0, 0, 0);
#pragma unroll
        for (int mi = 0; mi < 2; ++mi)
            acc[mi][2] = __builtin_amdgcn_mfma_f32_16x16x32_f16(af[mi], w2, acc[mi][2], 0, 0, 0);
    }

    // epilogue: f16 partial writes; bias only on ky==1; Q scaled by log2(e)
    int pixbase = (b * 64 + y) * 64 + xh * 32;
    bool addb = (ky == 1);
#pragma unroll
    for (int nj = 0; nj < 3; ++nj) {
        int co = nw * 48 + nj * 16 + lr;
        float bias = addb ? bc[co] : 0.f;
#pragma unroll
        for (int mi = 0; mi < 2; ++mi) {
#pragma unroll
            for (int r = 0; r < 4; ++r) {
                int px = mi * 16 + lk * 4 + r;
                float v = acc[mi][nj][r] + bias;
                size_t pix = pixbase + px;
                if (co < 32)
                    gpart[(size_t)ky * GP_ + pix * 32 + co] = (_Float16)(v * 1.44269504f);
                else if (co < 64)
                    fpart[(size_t)ky * GP_ + pix * 32 + (co - 32)] = (_Float16)v;
                else
                    hpart[(size_t)ky * HP_ + pix * 128 + (co - 64)] = (_Float16)v;
            }
        }
    }
}

// ---------------------------------------------------------------------------
// Fused pools (one launch): blocks [0,1024) = 2x2 maxpool of f partials -> Kf;
// blocks [1024,2048) = maxpool+transpose of h partials -> Vt.
// ---------------------------------------------------------------------------
__global__ __launch_bounds__(256) void pools_k(const _Float16* __restrict__ fp,
                                               const _Float16* __restrict__ hp,
                                               _Float16* __restrict__ Kf,
                                               _Float16* __restrict__ Vt) {
    __shared__ float t[32][33];
    int blk = blockIdx.x;
    int tid = threadIdx.x;
    if (blk < 1024) {
        int i = blk * 256 + tid;           // exactly B*NM*CG = 262144
        int c = i & 31;
        int t2 = i >> 5;
        int px = t2 & 31;
        int py = (t2 >> 5) & 31;
        int b  = t2 >> 10;
        size_t base = (((size_t)(b * 64 + py * 2)) * 64 + px * 2) * 32 + c;
        const _Float16* p1 = fp + GP_;
        const _Float16* p2 = fp + 2 * GP_;
        auto val = [&](size_t o) { return (float)fp[o] + (float)p1[o] + (float)p2[o]; };
        float v = fmaxf(fmaxf(val(base), val(base + 32)),
                        fmaxf(val(base + 64 * 32), val(base + 64 * 32 + 32)));
        Kf[i] = (_Float16)v;
        return;
    }
    int bx = blk - 1024;
    int b  = bx >> 7;
    int kt = (bx >> 2) & 31;
    int ct = bx & 3;
    const _Float16* p1 = hp + HP_;
    const _Float16* p2 = hp + 2 * (size_t)HP_;
#pragma unroll
    for (int i = 0; i < 4; ++i) {
        int e = tid + i * 256;
        int px = e >> 5, c = e & 31;
        size_t base = (((size_t)(b * 64 + kt * 2) * 64) + px * 2) * 128 + ct * 32 + c;
        auto val = [&](size_t o) { return (float)hp[o] + (float)p1[o] + (float)p2[o]; };
        float v = fmaxf(fmaxf(val(base), val(base + 128)),
                        fmaxf(val(base + 64 * 128), val(base + 64 * 128 + 128)));
        t[px][c] = v;
    }
    __syncthreads();
#pragma unroll
    for (int i = 0; i < 4; ++i) {
        int e = tid + i * 256;
        int c = e >> 5, px = e & 31;
        Vt[((size_t)b * 128 + ct * 32 + c) * 1024 + kt * 32 + px] = (_Float16)t[px][c];
    }
}

// ---------------------------------------------------------------------------
// Flash attention via f16 MFMA. 64 keys/iter. V k-tile staged in LDS
// (double-buffered, XOR-swizzled); K frags prefetched one tile ahead.
// Q = sum of 3 gpart planes. Output f16. setprio around MFMA clusters (T5).
// ---------------------------------------------------------------------------
constexpr int PP_ = 72;   // plds pitch (f16)

__global__ __launch_bounds__(256, 2) void attn_flash_k(
        const _Float16* __restrict__ Qp,   // gpart [3][B,4096,32] (x log2e)
        const _Float16* __restrict__ Kf,   // [B,1024,32]
        const _Float16* __restrict__ Vt,   // [B,128,1024]
        _Float16* __restrict__ wo) {       // [B,4096,128] f16
    __shared__ _Float16 plds[4][16][PP_];  // 9216 B
    __shared__ _Float16 vlds[2][8192];     // 2 x 16 KB
    int bb  = blockIdx.x >> 6;
    int qt  = blockIdx.x & 63;
    int wid = threadIdx.x >> 6;
    int l   = threadIdx.x & 63;
    int lr  = l & 15;
    int lg  = l >> 4;
    int qbase = qt * 64 + wid * 16;

    const _Float16* gp = Qp + ((size_t)bb * NQ_ + qbase + lr) * 32 + lg * 8;
    half8 bq = *reinterpret_cast<const half8*>(gp);
    bq = bq + *reinterpret_cast<const half8*>(gp + GP_);
    bq = bq + *reinterpret_cast<const half8*>(gp + 2 * GP_);

    const _Float16* Kb = Kf + (size_t)bb * NM_ * 32;
    const _Float16* Vb = Vt + (size_t)bb * 128 * NM_;

    int o0  = wid * 4096 + l * 16;
    int vr0 = o0 >> 7;
    int vc  = (o0 >> 4) & 7;
    int vsw = (vr0 & 7) << 4;
    int lsw = (lr & 7) << 4;

    f32x4 acc[8];
#pragma unroll
    for (int vt = 0; vt < 8; ++vt) acc[vt] = (f32x4)0.f;
    float m_run = -1.0e30f;
    float l_lane = 0.f;

    half8 ak0, ak1, ak2, ak3;
    f32x4 s0, s1, s2, s3;
    half4 ph0, ph1, ph2, ph3;
    float4 vst[4];

#define STAGE_LOAD(T)                                                              \
    {   const _Float16* vp = Vb + (size_t)(T) * 64 + (size_t)vr0 * NM_ + vc * 8;   \
        vst[0] = *reinterpret_cast<const float4*>(vp);                             \
        vst[1] = *reinterpret_cast<const float4*>(vp + 8 * NM_);                   \
        vst[2] = *reinterpret_cast<const float4*>(vp + 16 * NM_);                  \
        vst[3] = *reinterpret_cast<const float4*>(vp + 24 * NM_);                  \
    }

#define STAGE_WRITE(BUF)                                                           \
    {   char* vbp = (char*)vlds[BUF] + (o0 ^ vsw);                                 \
        *reinterpret_cast<float4*>(vbp)        = vst[0];                           \
        *reinterpret_cast<float4*>(vbp + 1024) = vst[1];                           \
        *reinterpret_cast<float4*>(vbp + 2048) = vst[2];                           \
        *reinterpret_cast<float4*>(vbp + 3072) = vst[3];                           \
    }

#define LOADK(T)                                                                   \
    {   const _Float16* kp = Kb + (size_t)(T) * 64 * 32;                           \
        ak0 = *reinterpret_cast<const half8*>(kp + (size_t)(lr)      * 32 + lg*8); \
        ak1 = *reinterpret_cast<const half8*>(kp + (size_t)(16 + lr) * 32 + lg*8); \
        ak2 = *reinterpret_cast<const half8*>(kp + (size_t)(32 + lr) * 32 + lg*8); \
        ak3 = *reinterpret_cast<const half8*>(kp + (size_t)(48 + lr) * 32 + lg*8); \
    }

#define QK()                                                                \
    {   __builtin_amdgcn_s_setprio(1);                                      \
        s0 = __builtin_amdgcn_mfma_f32_16x16x32_f16(ak0, bq, (f32x4)0.f, 0, 0, 0); \
        s1 = __builtin_amdgcn_mfma_f32_16x16x32_f16(ak1, bq, (f32x4)0.f, 0, 0, 0); \
        s2 = __builtin_amdgcn_mfma_f32_16x16x32_f16(ak2, bq, (f32x4)0.f, 0, 0, 0); \
        s3 = __builtin_amdgcn_mfma_f32_16x16x32_f16(ak3, bq, (f32x4)0.f, 0, 0, 0); \
        __builtin_amdgcn_s_setprio(0);                                      \
    }

#define SOFTMAX()                                                           \
    {   float lm = fmaxf(fmaxf(fmaxf(s0[0], s0[1]), fmaxf(s0[2], s0[3])),   \
                         fmaxf(fmaxf(s1[0], s1[1]), fmaxf(s1[2], s1[3])));  \
        lm = fmaxf(lm, fmaxf(fmaxf(fmaxf(s2[0], s2[1]), fmaxf(s2[2], s2[3])), \
                             fmaxf(fmaxf(s3[0], s3[1]), fmaxf(s3[2], s3[3])))); \
        if (__any(lm > m_run + 11.0f)) {                                    \
            float mx = lm;                                                  \
            mx = fmaxf(mx, __shfl_xor(mx, 16, 64));                         \
            mx = fmaxf(mx, __shfl_xor(mx, 32, 64));                         \
            float mnew  = fmaxf(m_run, mx);                                 \
            float alpha = exp2f(m_run - mnew);                              \
            l_lane *= alpha;                                                \
            _Pragma("unroll")                                               \
            for (int r = 0; r < 4; ++r) {                                   \
                float ar = __shfl(alpha, 4 * lg + r, 64);                   \
                _Pragma("unroll")                                           \
                for (int vt = 0; vt < 8; ++vt) acc[vt][r] *= ar;            \
            }                                                               \
            m_run = mnew;                                                   \
        }                                                                   \
        float ps = 0.f;                                                     \
        {   float p0 = exp2f(s0[0]-m_run), p1 = exp2f(s0[1]-m_run);         \
            float p2 = exp2f(s0[2]-m_run), p3 = exp2f(s0[3]-m_run);         \
            ps += (p0+p1)+(p2+p3);                                          \
            ph0[0]=(_Float16)p0; ph0[1]=(_Float16)p1;                       \
            ph0[2]=(_Float16)p2; ph0[3]=(_Float16)p3; }                     \
        {   float p0 = exp2f(s1[0]-m_run), p1 = exp2f(s1[1]-m_run);         \
            float p2 = exp2f(s1[2]-m_run), p3 = exp2f(s1[3]-m_run);         \
            ps += (p0+p1)+(p2+p3);                                          \
            ph1[0]=(_Float16)p0; ph1[1]=(_Float16)p1;                       \
            ph1[2]=(_Float16)p2; ph1[3]=(_Float16)p3; }                     \
        {   float p0 = exp2f(s2[0]-m_run), p1 = exp2f(s2[1]-m_run);         \
            float p2 = exp2f(s2[2]-m_run), p3 = exp2f(s2[3]-m_run);         \
            ps += (p0+p1)+(p2+p3);                                          \
            ph2[0]=(_Float16)p0; ph2[1]=(_Float16)p1;                       \
            ph2[2]=(_Float16)p2; ph2[3]=(_Float16)p3; }                     \
        {   float p0 = exp2f(s3[0]-m_run), p1 = exp2f(s3[1]-m_run);         \
            float p2 = exp2f(s3[2]-m_run), p3 = exp2f(s3[3]-m_run);         \
            ps += (p0+p1)+(p2+p3);                                          \
            ph3[0]=(_Float16)p0; ph3[1]=(_Float16)p1;                       \
            ph3[2]=(_Float16)p2; ph3[3]=(_Float16)p3; }                     \
        l_lane += ps;                                                       \
    }

#define WRITEP()                                                            \
    {   *reinterpret_cast<half4*>(&plds[wid][lr][ 0 + 4*lg]) = ph0;         \
        *reinterpret_cast<half4*>(&plds[wid][lr][16 + 4*lg]) = ph1;         \
        *reinterpret_cast<half4*>(&plds[wid][lr][32 + 4*lg]) = ph2;         \
        *reinterpret_cast<half4*>(&plds[wid][lr][48 + 4*lg]) = ph3;         \
    }

#define PV(BUF)                                                             \
    {   half8 ap0 = *reinterpret_cast<const half8*>(&plds[wid][lr][8*lg]);  \
        half8 ap1 = *reinterpret_cast<const half8*>(&plds[wid][lr][32 + 8*lg]); \
        const char* vbp = (const char*)vlds[BUF];                           \
        __builtin_amdgcn_s_setprio(1);                                      \
        _Pragma("unroll")                                                   \
        for (int vt = 0; vt < 8; ++vt) {                                    \
            int ra = (vt * 16 + lr) * 128;                                  \
            half8 bv = *reinterpret_cast<const half8*>(                     \
                vbp + ((ra + lg * 16) ^ lsw));                              \
            acc[vt] = __builtin_amdgcn_mfma_f32_16x16x32_f16(ap0, bv, acc[vt], 0, 0, 0); \
        }                                                                   \
        _Pragma("unroll")                                                   \
        for (int vt = 0; vt < 8; ++vt) {                                    \
            int ra = (vt * 16 + lr) * 128;                                  \
            half8 bv = *reinterpret_cast<const half8*>(                     \
                vbp + ((ra + (4 + lg) * 16) ^ lsw));                        \
            acc[vt] = __builtin_amdgcn_mfma_f32_16x16x32_f16(ap1, bv, acc[vt], 0, 0, 0); \
        }                                                                   \
        __builtin_amdgcn_s_setprio(0);                                      \
    }

    STAGE_LOAD(0);
    STAGE_WRITE(0);
    LOADK(0);
    __syncthreads();
    QK(); SOFTMAX();

    for (int t = 0; t < 16; ++t) {
        if (t < 15) { STAGE_LOAD(t + 1); LOADK(t + 1); }
        WRITEP();
        PV(t & 1);
        if (t < 15) STAGE_WRITE((t + 1) & 1);
        __syncthreads();
        if (t < 15) { QK(); SOFTMAX(); }
    }

#undef STAGE_LOAD
#undef STAGE_WRITE
#undef LOADK
#undef QK
#undef SOFTMAX
#undef WRITEP
#undef PV

    float lsum = l_lane;
    lsum += __shfl_xor(lsum, 16, 64);
    lsum += __shfl_xor(lsum, 32, 64);
    float inv = 1.f / lsum;
#pragma unroll
    for (int r = 0; r < 4; ++r) {
        float ir = __shfl(inv, 4 * lg + r, 64);
        _Float16* orow = wo + ((size_t)bb * NQ_ + qbase + 4 * lg + r) * 128 + lr;
#pragma unroll
        for (int vt = 0; vt < 8; ++vt) orow[vt * 16] = (_Float16)(acc[vt][r] * ir);
    }
}

// ---------------------------------------------------------------------------
// 1x1 conv (128->256) via f16 MFMA + bias + gated residual.
// ---------------------------------------------------------------------------
__global__ __launch_bounds__(256, 2) void conv1x1_mfma_k(
        const _Float16* __restrict__ wo, const _Float16* __restrict__ Wok,
        const float* __restrict__ bo, const float* __restrict__ X,
        const float* __restrict__ gate, float* __restrict__ out) {
    __shared__ char lds[64 * 256];   // 16 KB
    int pix0 = blockIdx.x * 64;
    int tid = threadIdx.x;
    int wq = tid >> 6;
    int l  = tid & 63;
    int lr = l & 15;
    int lg = l >> 4;

    {
        const float4* sp = reinterpret_cast<const float4*>(wo + (size_t)pix0 * 128);
#pragma unroll
        for (int j = 0; j < 4; ++j) {
            int c = tid + j * 256;
            int px = c >> 4;
            *reinterpret_cast<float4*>(lds + ((c * 16) ^ ((px & 7) << 4))) = sp[c];
        }
    }
    __syncthreads();

    f32x4 acc[4][4];
#pragma unroll
    for (int mi = 0; mi < 4; ++mi)
#pragma unroll
        for (int nj = 0; nj < 4; ++nj) acc[mi][nj] = (f32x4)0.f;

#pragma unroll
    for (int ks = 0; ks < 4; ++ks) {
        half8 ap[4];
#pragma unroll
        for (int mi = 0; mi < 4; ++mi) {
            int px = mi * 16 + lr;
            int ad = (px * 256 + ks * 64 + lg * 16) ^ ((px & 7) << 4);
            ap[mi] = *reinterpret_cast<const half8*>(lds + ad);
        }
#pragma unroll
        for (int nj = 0; nj < 4; ++nj) {
            int co16 = wq * 4 + nj;
            half8 bv = *reinterpret_cast<const half8*>(
                Wok + (((size_t)co16 * 4 + ks) * 64 + l) * 8);
#pragma unroll
            for (int mi = 0; mi < 4; ++mi)
                acc[mi][nj] = __builtin_amdgcn_mfma_f32_16x16x32_f16(ap[mi], bv, acc[mi][nj], 0, 0, 0);
        }
    }

    float gt = gate[0];
#pragma unroll
    for (int nj = 0; nj < 4; ++nj) {
        int co = wq * 64 + nj * 16 + lr;
        float bias = bo[co];
#pragma unroll
        for (int mi = 0; mi < 4; ++mi) {
#pragma unroll
            for (int r = 0; r < 4; ++r) {
                size_t o = (size_t)(pix0 + mi * 16 + lg * 4 + r) * 256 + co;
                out[o] = X[o] + gt * (acc[mi][nj][r] + bias);
            }
        }
    }
}

// ---------------------------------------------------------------------------
extern "C" void kernel_launch(void* const* d_in, const int* in_sizes, int n_in,
                              void* d_out, int out_size, void* d_ws, size_t ws_size,
                              hipStream_t stream) {
    const float* X    = (const float*)d_in[0];
    const float* Wf   = (const float*)d_in[1];
    const float* bf   = (const float*)d_in[2];
    const float* Wg   = (const float*)d_in[3];
    const float* bg   = (const float*)d_in[4];
    const float* Wh   = (const float*)d_in[5];
    const float* bh   = (const float*)d_in[6];
    const float* Wo   = (const float*)d_in[7];
    const float* bo   = (const float*)d_in[8];
    const float* gate = (const float*)d_in[9];
    float* out = (float*)d_out;

    // workspace layout (f16 units unless noted) — ~59 MB total
    _Float16* gpart = (_Float16*)d_ws;               // 3 * 1048576
    _Float16* fpart = gpart + 3 * (size_t)GP_;       // 3 * 1048576
    _Float16* hpart = fpart + 3 * (size_t)GP_;       // 3 * 4194304
    _Float16* Kf    = hpart + 3 * (size_t)HP_;       // 262144
    _Float16* Vt    = Kf + 262144;                   // 1048576
    _Float16* Wpk   = Vt + 1048576;                  // 589824
    float*    bc    = (float*)(Wpk + 589824);        // 192 f32
    _Float16* Wok   = (_Float16*)(bc + 192);         // 32768
    _Float16* Xpad  = Wok + 32768;                   // 8921088
    _Float16* wobuf = hpart;                         // alias: hpart dead after pools

    // 1) fused prep: Xpad + all weights + bias (one launch)
    int prep_n = NXC_ + NWPK_ + NWOK_ + 192;
    prep_all_k<<<(prep_n + 255) / 256, 256, 0, stream>>>(
        X, Wg, Wf, Wh, Wo, bg, bf, bh, Xpad, Wpk, Wok, bc);
    // 2) fused 3x3 convs via MFMA, ky-split, half-row blocks (grid 3072)
    conv_mfma_k<<<3 * B_ * 64 * 2, 256, 0, stream>>>(Xpad, Wpk, bc, gpart, fpart, hpart);
    // 3) fused pools (K + V-transpose) — one launch
    pools_k<<<2048, 256, 0, stream>>>(fpart, hpart, Kf, Vt);
    // 4) flash attention
    attn_flash_k<<<B_ * 64, 256, 0, stream>>>(gpart, Kf, Vt, wobuf);
    // 5) 1x1 conv via MFMA + residual
    conv1x1_mfma_k<<<(B_ * NQ_) / 64, 256, 0, stream>>>(wobuf, Wok, bo, X, gate, out);
}

// Round 17
// 104.066 us; speedup vs baseline: 1.1379x; 1.1379x over previous
//
#include <hip/hip_runtime.h>
#include <hip/hip_fp16.h>

// Problem constants
constexpr int B_  = 8;
constexpr int H_  = 64;
constexpr int W_  = 64;
constexpr int C_  = 256;
constexpr int CG_ = 32;
constexpr int CH_ = 128;
constexpr int NQ_ = 4096;
constexpr int NM_ = 1024;
constexpr int XP_ = 66;

constexpr int GP_ = 1048576;   // g/f partial plane stride (f16 elems)
constexpr int HP_ = 4194304;   // h partial plane stride

constexpr int NWPK_ = 12 * 9 * 8 * 64 * 8;   // 589824
constexpr int NWOK_ = 16 * 4 * 64 * 8;       // 32768
constexpr int NXC_  = B_ * XP_ * XP_ * 32;   // 1115136 Xpad half8-chunks

typedef __attribute__((ext_vector_type(8))) _Float16 half8;
typedef __attribute__((ext_vector_type(4))) _Float16 half4;
typedef __attribute__((ext_vector_type(4))) float    f32x4;

// ---------------------------------------------------------------------------
// Prep (single launch): Xpad f16 + Wpk + Wok + bc
// ---------------------------------------------------------------------------
__global__ void prep_all_k(const float* __restrict__ X,
                           const float* __restrict__ Wg, const float* __restrict__ Wf,
                           const float* __restrict__ Wh, const float* __restrict__ Wo,
                           const float* __restrict__ bg, const float* __restrict__ bf,
                           const float* __restrict__ bh,
                           _Float16* __restrict__ Xpad, _Float16* __restrict__ Wpk,
                           _Float16* __restrict__ Wok, float* __restrict__ bc) {
    int i = blockIdx.x * 256 + threadIdx.x;
    if (i < NXC_) {
        int c8 = i & 31;
        int px = i >> 5;
        int xx = px % XP_;
        int t  = px / XP_;
        int yy = t % XP_;
        int b  = t / XP_;
        half8 v = (half8)(_Float16)0.f;
        if (yy >= 1 && yy <= 64 && xx >= 1 && xx <= 64) {
            const float* s = X + (((size_t)(b * 64 + yy - 1) * 64) + (xx - 1)) * 256 + c8 * 8;
            float4 a  = *reinterpret_cast<const float4*>(s);
            float4 b2 = *reinterpret_cast<const float4*>(s + 4);
            v[0] = (_Float16)a.x;  v[1] = (_Float16)a.y;
            v[2] = (_Float16)a.z;  v[3] = (_Float16)a.w;
            v[4] = (_Float16)b2.x; v[5] = (_Float16)b2.y;
            v[6] = (_Float16)b2.z; v[7] = (_Float16)b2.w;
        }
        *reinterpret_cast<half8*>(Xpad + (size_t)i * 8) = v;
        return;
    }
    int iw = i - NXC_;
    if (iw < NWPK_) {
        int j    = iw & 7;
        int lane = (iw >> 3) & 63;
        int ks   = (iw >> 9) & 7;
        int tap  = (iw >> 12) % 9;
        int co16 = iw / 36864;
        int co = co16 * 16 + (lane & 15);
        int kk = tap * 256 + ks * 32 + (lane >> 4) * 8 + j;
        float v;
        if (co < 32)      v = Wg[(size_t)kk * 32  + co];
        else if (co < 64) v = Wf[(size_t)kk * 32  + (co - 32)];
        else              v = Wh[(size_t)kk * 128 + (co - 64)];
        Wpk[iw] = (_Float16)v;
        return;
    }
    int i2 = iw - NWPK_;
    if (i2 < NWOK_) {
        int j    = i2 & 7;
        int lane = (i2 >> 3) & 63;
        int ks   = (i2 >> 9) & 3;
        int co16 = i2 >> 11;
        int co = co16 * 16 + (lane & 15);
        int k  = ks * 32 + (lane >> 4) * 8 + j;
        Wok[i2] = (_Float16)Wo[(size_t)k * 256 + co];
        return;
    }
    int co = i2 - NWOK_;
    if (co < 192)
        bc[co] = (co < 32) ? bg[co] : (co < 64) ? bf[co - 32] : bh[co - 64];
}

// ---------------------------------------------------------------------------
// Fused 3x3 convs via f16 MFMA — r9's best-measured variant verbatim:
// ky-split (block = (ky,b,y)), ONE input row staged from Xpad f16 (33.8 KB),
// M64xN48 waves, depth-1 weight rotation, launch_bounds(256,4) -> VGPR~60,
// 4 blocks/CU. Measured 54-57 us, MfmaUtil ~20%.
// ---------------------------------------------------------------------------
__global__ __launch_bounds__(256, 4) void conv_mfma_k(
        const _Float16* __restrict__ Xpad, const _Float16* __restrict__ Wpk,
        const float* __restrict__ bc,
        _Float16* __restrict__ gpart, _Float16* __restrict__ fpart,
        _Float16* __restrict__ hpart) {
    __shared__ char lds[XP_ * 256 * 2];   // 33792 B
    int bid = blockIdx.x;
    int lg  = (bid & 7) * 192 + (bid >> 3);   // bijective chunked XCD map
    int ky  = lg % 3;
    int iy  = lg / 3;
    int b   = iy >> 6;
    int y   = iy & 63;
    int tid = threadIdx.x;
    int wid = tid >> 6;
    int l   = tid & 63;
    int lr  = l & 15;
    int lk  = l >> 4;

    // stage input row (b, y+ky) from zero-padded Xpad, swizzled
    {
        const float4* sp = reinterpret_cast<const float4*>(
            Xpad + ((size_t)(b * XP_ + y + ky) * XP_) * 256);
        float4 vst[8];
#pragma unroll
        for (int j = 0; j < 8; ++j) vst[j] = sp[tid + j * 256];
        float4 tl;
        if (tid < 64) tl = sp[tid + 2048];
#pragma unroll
        for (int j = 0; j < 8; ++j) {
            int c = tid + j * 256; int px = c >> 5;
            *reinterpret_cast<float4*>(lds + ((c * 16) ^ ((px & 7) << 4))) = vst[j];
        }
        if (tid < 64) {
            int c = tid + 2048; int px = c >> 5;
            *reinterpret_cast<float4*>(lds + ((c * 16) ^ ((px & 7) << 4))) = tl;
        }
    }
    __syncthreads();

    f32x4 acc[4][3];
#pragma unroll
    for (int mi = 0; mi < 4; ++mi)
#pragma unroll
        for (int nj = 0; nj < 3; ++nj) acc[mi][nj] = (f32x4)0.f;

    // weight loader: 3 co16 tiles for (tap, ks)
    auto ldw = [&](int tap, int ks, half8& d0, half8& d1, half8& d2) {
        const _Float16* p = Wpk + ((((size_t)(wid * 3) * 9 + tap) * 8 + ks) * 64 + l) * 8;
        d0 = *reinterpret_cast<const half8*>(p);
        d1 = *reinterpret_cast<const half8*>(p + 36864);
        d2 = *reinterpret_cast<const half8*>(p + 73728);
    };

    int tap0 = ky * 3;
    half8 b0, b1, b2, n0, n1, n2;
    ldw(tap0, 0, b0, b1, b2);
#pragma unroll
    for (int st = 0; st < 24; ++st) {
        int kx = st >> 3, ks = st & 7;
        if (st < 23) ldw(tap0 + ((st + 1) >> 3), (st + 1) & 7, n0, n1, n2);
        half8 af[4];
#pragma unroll
        for (int mi = 0; mi < 4; ++mi) {
            int px = mi * 16 + lr + kx;
            int ad = (px * 512 + ks * 64 + lk * 16) ^ ((px & 7) << 4);
            af[mi] = *reinterpret_cast<const half8*>(lds + ad);
        }
#pragma unroll
        for (int mi = 0; mi < 4; ++mi)
            acc[mi][0] = __builtin_amdgcn_mfma_f32_16x16x32_f16(af[mi], b0, acc[mi][0], 0, 0, 0);
#pragma unroll
        for (int mi = 0; mi < 4; ++mi)
            acc[mi][1] = __builtin_amdgcn_mfma_f32_16x16x32_f16(af[mi], b1, acc[mi][1], 0, 0, 0);
#pragma unroll
        for (int mi = 0; mi < 4; ++mi)
            acc[mi][2] = __builtin_amdgcn_mfma_f32_16x16x32_f16(af[mi], b2, acc[mi][2], 0, 0, 0);
        b0 = n0; b1 = n1; b2 = n2;
    }

    // epilogue: f16 partial writes; bias only on ky==1; Q scaled by log2(e)
    int pixbase = (b * 64 + y) * 64;
    bool addb = (ky == 1);
#pragma unroll
    for (int nj = 0; nj < 3; ++nj) {
        int co = wid * 48 + nj * 16 + lr;
        float bias = addb ? bc[co] : 0.f;
#pragma unroll
        for (int mi = 0; mi < 4; ++mi) {
#pragma unroll
            for (int r = 0; r < 4; ++r) {
                int x = mi * 16 + lk * 4 + r;
                float v = acc[mi][nj][r] + bias;
                size_t pix = pixbase + x;
                if (co < 32)
                    gpart[(size_t)ky * GP_ + pix * 32 + co] = (_Float16)(v * 1.44269504f);
                else if (co < 64)
                    fpart[(size_t)ky * GP_ + pix * 32 + (co - 32)] = (_Float16)v;
                else
                    hpart[(size_t)ky * HP_ + pix * 128 + (co - 64)] = (_Float16)v;
            }
        }
    }
}

// ---------------------------------------------------------------------------
// Fused pools (one launch): blocks [0,1024) -> Kf; [1024,2048) -> Vt.
// ---------------------------------------------------------------------------
__global__ __launch_bounds__(256) void pools_k(const _Float16* __restrict__ fp,
                                               const _Float16* __restrict__ hp,
                                               _Float16* __restrict__ Kf,
                                               _Float16* __restrict__ Vt) {
    __shared__ float t[32][33];
    int blk = blockIdx.x;
    int tid = threadIdx.x;
    if (blk < 1024) {
        int i = blk * 256 + tid;
        int c = i & 31;
        int t2 = i >> 5;
        int px = t2 & 31;
        int py = (t2 >> 5) & 31;
        int b  = t2 >> 10;
        size_t base = (((size_t)(b * 64 + py * 2)) * 64 + px * 2) * 32 + c;
        const _Float16* p1 = fp + GP_;
        const _Float16* p2 = fp + 2 * GP_;
        auto val = [&](size_t o) { return (float)fp[o] + (float)p1[o] + (float)p2[o]; };
        float v = fmaxf(fmaxf(val(base), val(base + 32)),
                        fmaxf(val(base + 64 * 32), val(base + 64 * 32 + 32)));
        Kf[i] = (_Float16)v;
        return;
    }
    int bx = blk - 1024;
    int b  = bx >> 7;
    int kt = (bx >> 2) & 31;
    int ct = bx & 3;
    const _Float16* p1 = hp + HP_;
    const _Float16* p2 = hp + 2 * (size_t)HP_;
#pragma unroll
    for (int i = 0; i < 4; ++i) {
        int e = tid + i * 256;
        int px = e >> 5, c = e & 31;
        size_t base = (((size_t)(b * 64 + kt * 2) * 64) + px * 2) * 128 + ct * 32 + c;
        auto val = [&](size_t o) { return (float)hp[o] + (float)p1[o] + (float)p2[o]; };
        float v = fmaxf(fmaxf(val(base), val(base + 128)),
                        fmaxf(val(base + 64 * 128), val(base + 64 * 128 + 128)));
        t[px][c] = v;
    }
    __syncthreads();
#pragma unroll
    for (int i = 0; i < 4; ++i) {
        int e = tid + i * 256;
        int c = e >> 5, px = e & 31;
        Vt[((size_t)b * 128 + ct * 32 + c) * 1024 + kt * 32 + px] = (_Float16)t[px][c];
    }
}

// ---------------------------------------------------------------------------
// Flash attention via f16 MFMA (V LDS-staged dbuf, K prefetch, setprio).
// ---------------------------------------------------------------------------
constexpr int PP_ = 72;

__global__ __launch_bounds__(256, 2) void attn_flash_k(
        const _Float16* __restrict__ Qp,   // gpart [3][B,4096,32] (x log2e)
        const _Float16* __restrict__ Kf,   // [B,1024,32]
        const _Float16* __restrict__ Vt,   // [B,128,1024]
        _Float16* __restrict__ wo) {       // [B,4096,128] f16
    __shared__ _Float16 plds[4][16][PP_];
    __shared__ _Float16 vlds[2][8192];
    int bb  = blockIdx.x >> 6;
    int qt  = blockIdx.x & 63;
    int wid = threadIdx.x >> 6;
    int l   = threadIdx.x & 63;
    int lr  = l & 15;
    int lg  = l >> 4;
    int qbase = qt * 64 + wid * 16;

    const _Float16* gp = Qp + ((size_t)bb * NQ_ + qbase + lr) * 32 + lg * 8;
    half8 bq = *reinterpret_cast<const half8*>(gp);
    bq = bq + *reinterpret_cast<const half8*>(gp + GP_);
    bq = bq + *reinterpret_cast<const half8*>(gp + 2 * GP_);

    const _Float16* Kb = Kf + (size_t)bb * NM_ * 32;
    const _Float16* Vb = Vt + (size_t)bb * 128 * NM_;

    int o0  = wid * 4096 + l * 16;
    int vr0 = o0 >> 7;
    int vc  = (o0 >> 4) & 7;
    int vsw = (vr0 & 7) << 4;
    int lsw = (lr & 7) << 4;

    f32x4 acc[8];
#pragma unroll
    for (int vt = 0; vt < 8; ++vt) acc[vt] = (f32x4)0.f;
    float m_run = -1.0e30f;
    float l_lane = 0.f;

    half8 ak0, ak1, ak2, ak3;
    f32x4 s0, s1, s2, s3;
    half4 ph0, ph1, ph2, ph3;
    float4 vst[4];

#define STAGE_LOAD(T)                                                              \
    {   const _Float16* vp = Vb + (size_t)(T) * 64 + (size_t)vr0 * NM_ + vc * 8;   \
        vst[0] = *reinterpret_cast<const float4*>(vp);                             \
        vst[1] = *reinterpret_cast<const float4*>(vp + 8 * NM_);                   \
        vst[2] = *reinterpret_cast<const float4*>(vp + 16 * NM_);                  \
        vst[3] = *reinterpret_cast<const float4*>(vp + 24 * NM_);                  \
    }

#define STAGE_WRITE(BUF)                                                           \
    {   char* vbp = (char*)vlds[BUF] + (o0 ^ vsw);                                 \
        *reinterpret_cast<float4*>(vbp)        = vst[0];                           \
        *reinterpret_cast<float4*>(vbp + 1024) = vst[1];                           \
        *reinterpret_cast<float4*>(vbp + 2048) = vst[2];                           \
        *reinterpret_cast<float4*>(vbp + 3072) = vst[3];                           \
    }

#define LOADK(T)                                                                   \
    {   const _Float16* kp = Kb + (size_t)(T) * 64 * 32;                           \
        ak0 = *reinterpret_cast<const half8*>(kp + (size_t)(lr)      * 32 + lg*8); \
        ak1 = *reinterpret_cast<const half8*>(kp + (size_t)(16 + lr) * 32 + lg*8); \
        ak2 = *reinterpret_cast<const half8*>(kp + (size_t)(32 + lr) * 32 + lg*8); \
        ak3 = *reinterpret_cast<const half8*>(kp + (size_t)(48 + lr) * 32 + lg*8); \
    }

#define QK()                                                                \
    {   __builtin_amdgcn_s_setprio(1);                                      \
        s0 = __builtin_amdgcn_mfma_f32_16x16x32_f16(ak0, bq, (f32x4)0.f, 0, 0, 0); \
        s1 = __builtin_amdgcn_mfma_f32_16x16x32_f16(ak1, bq, (f32x4)0.f, 0, 0, 0); \
        s2 = __builtin_amdgcn_mfma_f32_16x16x32_f16(ak2, bq, (f32x4)0.f, 0, 0, 0); \
        s3 = __builtin_amdgcn_mfma_f32_16x16x32_f16(ak3, bq, (f32x4)0.f, 0, 0, 0); \
        __builtin_amdgcn_s_setprio(0);                                      \
    }

#define SOFTMAX()                                                           \
    {   float lm = fmaxf(fmaxf(fmaxf(s0[0], s0[1]), fmaxf(s0[2], s0[3])),   \
                         fmaxf(fmaxf(s1[0], s1[1]), fmaxf(s1[2], s1[3])));  \
        lm = fmaxf(lm, fmaxf(fmaxf(fmaxf(s2[0], s2[1]), fmaxf(s2[2], s2[3])), \
                             fmaxf(fmaxf(s3[0], s3[1]), fmaxf(s3[2], s3[3])))); \
        if (__any(lm > m_run + 11.0f)) {                                    \
            float mx = lm;                                                  \
            mx = fmaxf(mx, __shfl_xor(mx, 16, 64));                         \
            mx = fmaxf(mx, __shfl_xor(mx, 32, 64));                         \
            float mnew  = fmaxf(m_run, mx);                                 \
            float alpha = exp2f(m_run - mnew);                              \
            l_lane *= alpha;                                                \
            _Pragma("unroll")                                               \
            for (int r = 0; r < 4; ++r) {                                   \
                float ar = __shfl(alpha, 4 * lg + r, 64);                   \
                _Pragma("unroll")                                           \
                for (int vt = 0; vt < 8; ++vt) acc[vt][r] *= ar;            \
            }                                                               \
            m_run = mnew;                                                   \
        }                                                                   \
        float ps = 0.f;                                                     \
        {   float p0 = exp2f(s0[0]-m_run), p1 = exp2f(s0[1]-m_run);         \
            float p2 = exp2f(s0[2]-m_run), p3 = exp2f(s0[3]-m_run);         \
            ps += (p0+p1)+(p2+p3);                                          \
            ph0[0]=(_Float16)p0; ph0[1]=(_Float16)p1;                       \
            ph0[2]=(_Float16)p2; ph0[3]=(_Float16)p3; }                     \
        {   float p0 = exp2f(s1[0]-m_run), p1 = exp2f(s1[1]-m_run);         \
            float p2 = exp2f(s1[2]-m_run), p3 = exp2f(s1[3]-m_run);         \
            ps += (p0+p1)+(p2+p3);                                          \
            ph1[0]=(_Float16)p0; ph1[1]=(_Float16)p1;                       \
            ph1[2]=(_Float16)p2; ph1[3]=(_Float16)p3; }                     \
        {   float p0 = exp2f(s2[0]-m_run), p1 = exp2f(s2[1]-m_run);         \
            float p2 = exp2f(s2[2]-m_run), p3 = exp2f(s2[3]-m_run);         \
            ps += (p0+p1)+(p2+p3);                                          \
            ph2[0]=(_Float16)p0; ph2[1]=(_Float16)p1;                       \
            ph2[2]=(_Float16)p2; ph2[3]=(_Float16)p3; }                     \
        {   float p0 = exp2f(s3[0]-m_run), p1 = exp2f(s3[1]-m_run);         \
            float p2 = exp2f(s3[2]-m_run), p3 = exp2f(s3[3]-m_run);         \
            ps += (p0+p1)+(p2+p3);                                          \
            ph3[0]=(_Float16)p0; ph3[1]=(_Float16)p1;                       \
            ph3[2]=(_Float16)p2; ph3[3]=(_Float16)p3; }                     \
        l_lane += ps;                                                       \
    }

#define WRITEP()                                                            \
    {   *reinterpret_cast<half4*>(&plds[wid][lr][ 0 + 4*lg]) = ph0;         \
        *reinterpret_cast<half4*>(&plds[wid][lr][16 + 4*lg]) = ph1;         \
        *reinterpret_cast<half4*>(&plds[wid][lr][32 + 4*lg]) = ph2;         \
        *reinterpret_cast<half4*>(&plds[wid][lr][48 + 4*lg]) = ph3;         \
    }

#define PV(BUF)                                                             \
    {   half8 ap0 = *reinterpret_cast<const half8*>(&plds[wid][lr][8*lg]);  \
        half8 ap1 = *reinterpret_cast<const half8*>(&plds[wid][lr][32 + 8*lg]); \
        const char* vbp = (const char*)vlds[BUF];                           \
        __builtin_amdgcn_s_setprio(1);                                      \
        _Pragma("unroll")                                                   \
        for (int vt = 0; vt < 8; ++vt) {                                    \
            int ra = (vt * 16 + lr) * 128;                                  \
            half8 bv = *reinterpret_cast<const half8*>(                     \
                vbp + ((ra + lg * 16) ^ lsw));                              \
            acc[vt] = __builtin_amdgcn_mfma_f32_16x16x32_f16(ap0, bv, acc[vt], 0, 0, 0); \
        }                                                                   \
        _Pragma("unroll")                                                   \
        for (int vt = 0; vt < 8; ++vt) {                                    \
            int ra = (vt * 16 + lr) * 128;                                  \
            half8 bv = *reinterpret_cast<const half8*>(                     \
                vbp + ((ra + (4 + lg) * 16) ^ lsw));                        \
            acc[vt] = __builtin_amdgcn_mfma_f32_16x16x32_f16(ap1, bv, acc[vt], 0, 0, 0); \
        }                                                                   \
        __builtin_amdgcn_s_setprio(0);                                      \
    }

    STAGE_LOAD(0);
    STAGE_WRITE(0);
    LOADK(0);
    __syncthreads();
    QK(); SOFTMAX();

    for (int t = 0; t < 16; ++t) {
        if (t < 15) { STAGE_LOAD(t + 1); LOADK(t + 1); }
        WRITEP();
        PV(t & 1);
        if (t < 15) STAGE_WRITE((t + 1) & 1);
        __syncthreads();
        if (t < 15) { QK(); SOFTMAX(); }
    }

#undef STAGE_LOAD
#undef STAGE_WRITE
#undef LOADK
#undef QK
#undef SOFTMAX
#undef WRITEP
#undef PV

    float lsum = l_lane;
    lsum += __shfl_xor(lsum, 16, 64);
    lsum += __shfl_xor(lsum, 32, 64);
    float inv = 1.f / lsum;
#pragma unroll
    for (int r = 0; r < 4; ++r) {
        float ir = __shfl(inv, 4 * lg + r, 64);
        _Float16* orow = wo + ((size_t)bb * NQ_ + qbase + 4 * lg + r) * 128 + lr;
#pragma unroll
        for (int vt = 0; vt < 8; ++vt) orow[vt * 16] = (_Float16)(acc[vt][r] * ir);
    }
}

// ---------------------------------------------------------------------------
// 1x1 conv (128->256) via f16 MFMA + bias + gated residual.
// ---------------------------------------------------------------------------
__global__ __launch_bounds__(256, 2) void conv1x1_mfma_k(
        const _Float16* __restrict__ wo, const _Float16* __restrict__ Wok,
        const float* __restrict__ bo, const float* __restrict__ X,
        const float* __restrict__ gate, float* __restrict__ out) {
    __shared__ char lds[64 * 256];
    int pix0 = blockIdx.x * 64;
    int tid = threadIdx.x;
    int wq = tid >> 6;
    int l  = tid & 63;
    int lr = l & 15;
    int lg = l >> 4;

    {
        const float4* sp = reinterpret_cast<const float4*>(wo + (size_t)pix0 * 128);
#pragma unroll
        for (int j = 0; j < 4; ++j) {
            int c = tid + j * 256;
            int px = c >> 4;
            *reinterpret_cast<float4*>(lds + ((c * 16) ^ ((px & 7) << 4))) = sp[c];
        }
    }
    __syncthreads();

    f32x4 acc[4][4];
#pragma unroll
    for (int mi = 0; mi < 4; ++mi)
#pragma unroll
        for (int nj = 0; nj < 4; ++nj) acc[mi][nj] = (f32x4)0.f;

#pragma unroll
    for (int ks = 0; ks < 4; ++ks) {
        half8 ap[4];
#pragma unroll
        for (int mi = 0; mi < 4; ++mi) {
            int px = mi * 16 + lr;
            int ad = (px * 256 + ks * 64 + lg * 16) ^ ((px & 7) << 4);
            ap[mi] = *reinterpret_cast<const half8*>(lds + ad);
        }
#pragma unroll
        for (int nj = 0; nj < 4; ++nj) {
            int co16 = wq * 4 + nj;
            half8 bv = *reinterpret_cast<const half8*>(
                Wok + (((size_t)co16 * 4 + ks) * 64 + l) * 8);
#pragma unroll
            for (int mi = 0; mi < 4; ++mi)
                acc[mi][nj] = __builtin_amdgcn_mfma_f32_16x16x32_f16(ap[mi], bv, acc[mi][nj], 0, 0, 0);
        }
    }

    float gt = gate[0];
#pragma unroll
    for (int nj = 0; nj < 4; ++nj) {
        int co = wq * 64 + nj * 16 + lr;
        float bias = bo[co];
#pragma unroll
        for (int mi = 0; mi < 4; ++mi) {
#pragma unroll
            for (int r = 0; r < 4; ++r) {
                size_t o = (size_t)(pix0 + mi * 16 + lg * 4 + r) * 256 + co;
                out[o] = X[o] + gt * (acc[mi][nj][r] + bias);
            }
        }
    }
}

// ---------------------------------------------------------------------------
extern "C" void kernel_launch(void* const* d_in, const int* in_sizes, int n_in,
                              void* d_out, int out_size, void* d_ws, size_t ws_size,
                              hipStream_t stream) {
    const float* X    = (const float*)d_in[0];
    const float* Wf   = (const float*)d_in[1];
    const float* bf   = (const float*)d_in[2];
    const float* Wg   = (const float*)d_in[3];
    const float* bg   = (const float*)d_in[4];
    const float* Wh   = (const float*)d_in[5];
    const float* bh   = (const float*)d_in[6];
    const float* Wo   = (const float*)d_in[7];
    const float* bo   = (const float*)d_in[8];
    const float* gate = (const float*)d_in[9];
    float* out = (float*)d_out;

    // workspace layout (f16 units unless noted) — ~59 MB total
    _Float16* gpart = (_Float16*)d_ws;               // 3 * 1048576
    _Float16* fpart = gpart + 3 * (size_t)GP_;       // 3 * 1048576
    _Float16* hpart = fpart + 3 * (size_t)GP_;       // 3 * 4194304
    _Float16* Kf    = hpart + 3 * (size_t)HP_;       // 262144
    _Float16* Vt    = Kf + 262144;                   // 1048576
    _Float16* Wpk   = Vt + 1048576;                  // 589824
    float*    bc    = (float*)(Wpk + 589824);        // 192 f32
    _Float16* Wok   = (_Float16*)(bc + 192);         // 32768
    _Float16* Xpad  = Wok + 32768;                   // 8921088
    _Float16* wobuf = hpart;                         // alias: hpart dead after pools

    // 1) fused prep: Xpad + all weights + bias (one launch)
    int prep_n = NXC_ + NWPK_ + NWOK_ + 192;
    prep_all_k<<<(prep_n + 255) / 256, 256, 0, stream>>>(
        X, Wg, Wf, Wh, Wo, bg, bf, bh, Xpad, Wpk, Wok, bc);
    // 2) fused 3x3 convs via MFMA, ky-split 1-row (r9 best, grid 1536)
    conv_mfma_k<<<3 * B_ * H_, 256, 0, stream>>>(Xpad, Wpk, bc, gpart, fpart, hpart);
    // 3) fused pools (K + V-transpose)
    pools_k<<<2048, 256, 0, stream>>>(fpart, hpart, Kf, Vt);
    // 4) flash attention
    attn_flash_k<<<B_ * 64, 256, 0, stream>>>(gpart, Kf, Vt, wobuf);
    // 5) 1x1 conv via MFMA + residual
    conv1x1_mfma_k<<<(B_ * NQ_) / 64, 256, 0, stream>>>(wobuf, Wok, bo, X, gate, out);
}